// Round 12
// baseline (145.454 us; speedup 1.0000x reference)
//
#include <hip/hip_runtime.h>
#include <stdint.h>

#define NPRIM 65536
#define NT 16
#define T_TILES 256
#define NBKT 2048          // depth-VALUE buckets: floor(depth * 204.8)
#define BCAP 256           // per-bucket cap (avg 32, Poisson; unreachable)
#define NBLK 64            // compute/scatter blocks (1024 elems each)
#define CTHR 512
#define CBLK 512           // 256 tile blocks + 256 fill blocks
#define FILLB (CBLK - T_TILES)

typedef unsigned long long u64;
typedef unsigned int u32;

// monotone value-based bucket: depth in [0,10) -> [0,2048)
__device__ __forceinline__ u32 dbucket(float d) {
    u32 b = (u32)(d * 204.8f);          // monotone; equal depths -> same bucket
    return b > (NBKT - 1) ? (NBKT - 1) : b;
}

// ---------------------------------------------------------------------------
// Kernel 1: bounds + keys(lrank|depth|prim) + per-block tile & bucket
// histogram rows (no global atomics, no zero-init requirements).
// ---------------------------------------------------------------------------
__global__ __launch_bounds__(256) void k_compute(
    const float2* __restrict__ pos2d, const float* __restrict__ radius,
    const float* __restrict__ depth, u64* __restrict__ keysRaw,
    u32* __restrict__ bounds, u32* __restrict__ counts_blk,
    u32* __restrict__ bh)
{
    __shared__ u32 hist[T_TILES];
    __shared__ u32 bhist[NBKT];
    int tid = threadIdx.x;
    hist[tid] = 0;
    for (int j = tid; j < NBKT; j += 256) bhist[j] = 0;
    __syncthreads();

    int base = blockIdx.x * 1024;
    const float mx = (float)(16.0 - 1e-5);  // matches python 16 - 1e-5 -> f32
    #pragma unroll
    for (int q = 0; q < 4; ++q) {
        int i = base + q * 256 + tid;
        float2 p = pos2d[i];
        float r = radius[i];
        float fx = p.x / 68.0f;             // BLOCK_W == BLOCK_H == 68 (ref bug preserved)
        float fy = p.y / 68.0f;
        int xmin = (int)fminf(fmaxf(fx - r, 0.0f), mx);
        int xmax = (int)fminf(fmaxf(fx + r, 0.0f), mx);
        int ymin = (int)fminf(fmaxf(fy - r, 0.0f), mx);
        int ymax = (int)fminf(fmaxf(fy + r, 0.0f), mx);
        bounds[i] = (u32)(xmin | (xmax << 4) | (ymin << 8) | (ymax << 12));
        float d = depth[i];
        // lrank: position within (block,bucket) — atomic order OK (keys unique)
        u32 lrank = atomicAdd(&bhist[dbucket(d)], 1u);
        // key: [0,16) prim, [16,48) depth bits (>=0 -> orders as uint), [48,64) lrank
        keysRaw[i] = ((u64)lrank << 48) | ((u64)__float_as_uint(d) << 16) | (u32)i;
        for (int ty = ymin; ty <= ymax; ++ty)
            for (int tx = xmin; tx <= xmax; ++tx)
                atomicAdd(&hist[ty * NT + tx], 1u);
    }
    __syncthreads();
    counts_blk[blockIdx.x * 256 + tid] = hist[tid];
    for (int j = tid; j < NBKT; j += 256) bh[blockIdx.x * NBKT + j] = bhist[j];
}

// ---------------------------------------------------------------------------
// Kernel 2: atomic-free scatter. Each block derives global bucket bases +
// its own partials from bh; pos = loff[d] + lrank. Block 0 publishes
// bucket_base / bucket_count for k_bsort.
// ---------------------------------------------------------------------------
__global__ __launch_bounds__(256) void k_scatter(
    const u64* __restrict__ keysRaw, const u32* __restrict__ bh,
    u64* __restrict__ keysBkt, u32* __restrict__ bucket_base,
    u32* __restrict__ bucket_count)
{
    __shared__ u32 loff[NBKT];
    __shared__ u32 wsum[4];
    int tid = threadIdx.x, lane = tid & 63, wave = tid >> 6;
    int blk = blockIdx.x;

    // thread owns digits [tid*8, tid*8+8)
    u32 c8[8] = {0,0,0,0,0,0,0,0};
    u32 p8[8] = {0,0,0,0,0,0,0,0};
    for (int b = 0; b < NBLK; ++b) {
        const uint4* row = (const uint4*)(bh + b * NBKT + tid * 8);
        uint4 h0 = row[0], h1 = row[1];
        u32 h[8] = {h0.x, h0.y, h0.z, h0.w, h1.x, h1.y, h1.z, h1.w};
        #pragma unroll
        for (int j = 0; j < 8; ++j) {
            if (b < blk) p8[j] += h[j];
            c8[j] += h[j];
        }
    }
    u32 sum8 = 0;
    #pragma unroll
    for (int j = 0; j < 8; ++j) sum8 += c8[j];
    u32 v = sum8;
    #pragma unroll
    for (int d = 1; d < 64; d <<= 1) {
        u32 t = __shfl_up(v, d, 64);
        if (lane >= d) v += t;
    }
    if (lane == 63) wsum[wave] = v;
    __syncthreads();
    u32 add = 0;
    for (int w = 0; w < wave; ++w) add += wsum[w];
    u32 run = v + add - sum8;                 // exclusive global base of digit tid*8
    #pragma unroll
    for (int j = 0; j < 8; ++j) {
        loff[tid * 8 + j] = run + p8[j];
        if (blk == 0) {
            bucket_base[tid * 8 + j] = run;
            bucket_count[tid * 8 + j] = c8[j];
        }
        run += c8[j];
    }
    __syncthreads();

    int base = blk * 1024;
    #pragma unroll
    for (int q = 0; q < 4; ++q) {
        u64 key = keysRaw[base + q * 256 + tid];
        u32 d = dbucket(__uint_as_float((u32)(key >> 16)));  // identical expr
        u32 lrank = (u32)(key >> 48);
        keysBkt[loff[d] + lrank] = key & 0x0000FFFFFFFFFFFFull;
    }
}

// ---------------------------------------------------------------------------
// Kernel 3: one WAVE per bucket; rank by full unique 48-bit key; write
// entries[base+rank] = bounds<<16 | prim.
// ---------------------------------------------------------------------------
__global__ __launch_bounds__(256) void k_bsort(
    const u64* __restrict__ keysBkt, const u32* __restrict__ bucket_base,
    const u32* __restrict__ bucket_count, const u32* __restrict__ bounds,
    u32* __restrict__ entries)
{
    __shared__ u64 buf[4][BCAP];
    int tid = threadIdx.x, lane = tid & 63, wave = tid >> 6;
    int bucket = blockIdx.x * 4 + wave;
    u32 base = bucket_base[bucket];
    u32 n = bucket_count[bucket];
    if (n > BCAP) n = BCAP;                   // unreachable (Poisson(32) tail)
    #pragma unroll
    for (int t = 0; t < 4; ++t) {
        u32 i = (u32)lane + 64u * t;
        if (i < n) buf[wave][i] = keysBkt[base + i];
    }
    __syncthreads();
    #pragma unroll
    for (int t = 0; t < 4; ++t) {
        u32 i = (u32)lane + 64u * t;
        if (i < n) {
            u64 ki = buf[wave][i];
            u32 r = 0;
            for (u32 j = 0; j < n; ++j) r += (buf[wave][j] < ki);
            u32 prim = (u32)ki & 0xFFFFu;
            entries[base + r] = (bounds[prim] << 16) | prim;
        }
    }
}

// ---------------------------------------------------------------------------
// Kernel 4: compact + fill, 2-barrier chunk scheme. Every block redundantly
// derives tile offsets from counts_blk (block 0 writes tile_count output).
// Blocks [0,256): per-tile ordered compaction; [256,512): -1 fill.
// ---------------------------------------------------------------------------
__global__ __launch_bounds__(CTHR) void k_compact(
    const uint4* __restrict__ entries4, const u32* __restrict__ counts_blk,
    int* __restrict__ tile_count, int* __restrict__ out_idx)
{
    __shared__ u32 cnt[T_TILES];
    __shared__ u32 excl[T_TILES];
    __shared__ u32 wsum[4];
    __shared__ u32 chunkcnt[64];
    __shared__ u32 chunkoff[64];
    int b = blockIdx.x, tid = threadIdx.x, lane = tid & 63, wave = tid >> 6;

    // ---- tile counts + scan (threads 0-255) ----
    if (tid < 256) {
        u32 s = 0;
        for (int bb = 0; bb < NBLK; ++bb) s += counts_blk[bb * 256 + tid];
        cnt[tid] = s;
    }
    __syncthreads();
    if (tid < 256) {
        u32 c = cnt[tid], v = c;
        #pragma unroll
        for (int d = 1; d < 64; d <<= 1) {
            u32 t = __shfl_up(v, d, 64);
            if (lane >= d) v += t;
        }
        if (lane == 63) wsum[wave] = v;
        excl[tid] = v;                        // wave-inclusive, fixed below
    }
    __syncthreads();
    if (tid < 256) {
        u32 add = 0;
        for (int w = 0; w < wave; ++w) add += wsum[w];
        u32 incl = excl[tid] + add;
        excl[tid] = incl - cnt[tid];
        cnt[tid] = incl;
        if (b == 0) tile_count[tid] = (int)incl;   // reference output 0
    }
    __syncthreads();
    u32 total = cnt[T_TILES - 1];

    if (b >= T_TILES) {
        // ---- -1 fill of [total, T*N) ----
        const u32 end = (u32)T_TILES * (u32)NPRIM;   // divisible by 4
        u32 s4 = (total + 3u) & ~3u;
        if (b == T_TILES && tid < (int)(s4 - total)) out_idx[total + tid] = -1;
        u32 n4 = (end - s4) >> 2;
        int4* o4 = (int4*)(out_idx + s4);            // 16B aligned
        int4 m1 = make_int4(-1, -1, -1, -1);
        u32 gid = (u32)(b - T_TILES) * (u32)CTHR + (u32)tid;
        for (u32 i = gid; i < n4; i += (u32)FILLB * (u32)CTHR) o4[i] = m1;
        return;
    }

    int tile = b, tx = tile & 15, ty = tile >> 4;
    u32 base0 = excl[tile];
    u64 lmask = (1ull << lane) - 1;

    // ---- phase A: per-wave chunk member counts (chunk = 1024 entries) ----
    for (int cc = 0; cc < 8; ++cc) {
        int ch = wave * 8 + cc;
        u32 cs = 0;
        #pragma unroll
        for (int k = 0; k < 4; ++k) {
            uint4 e = entries4[ch * 256 + k * 64 + lane];
            u32 ev[4] = {e.x, e.y, e.z, e.w};
            #pragma unroll
            for (int q = 0; q < 4; ++q) {
                u32 bb2 = ev[q] >> 16;
                bool m = (tx >= (int)(bb2 & 15)) && (tx <= (int)((bb2 >> 4) & 15))
                      && (ty >= (int)((bb2 >> 8) & 15)) && (ty <= (int)((bb2 >> 12) & 15));
                cs += (u32)__popcll(__ballot(m));
            }
        }
        if (lane == 0) chunkcnt[ch] = cs;
    }
    __syncthreads();
    // ---- chunk offsets: exclusive scan of 64 counts (wave 0) ----
    if (tid < 64) {
        u32 c2 = chunkcnt[tid], v2 = c2;
        #pragma unroll
        for (int d = 1; d < 64; d <<= 1) {
            u32 t = __shfl_up(v2, d, 64);
            if (lane >= d) v2 += t;
        }
        chunkoff[tid] = base0 + v2 - c2;
    }
    __syncthreads();

    // ---- phase C: ordered writes ----
    for (int cc = 0; cc < 8; ++cc) {
        int ch = wave * 8 + cc;
        u32 run = chunkoff[ch];
        #pragma unroll
        for (int k = 0; k < 4; ++k) {
            uint4 e = entries4[ch * 256 + k * 64 + lane];
            u32 ev[4] = {e.x, e.y, e.z, e.w};
            bool m[4]; u64 bal[4];
            #pragma unroll
            for (int q = 0; q < 4; ++q) {
                u32 bb2 = ev[q] >> 16;
                m[q] = (tx >= (int)(bb2 & 15)) && (tx <= (int)((bb2 >> 4) & 15))
                    && (ty >= (int)((bb2 >> 8) & 15)) && (ty <= (int)((bb2 >> 12) & 15));
                bal[q] = __ballot(m[q]);
            }
            u32 pre = (u32)(__popcll(bal[0] & lmask) + __popcll(bal[1] & lmask)
                          + __popcll(bal[2] & lmask) + __popcll(bal[3] & lmask));
            #pragma unroll
            for (int q = 0; q < 4; ++q) {
                if (m[q]) { out_idx[run + pre] = (int)(ev[q] & 0xFFFFu); pre++; }
            }
            run += (u32)(__popcll(bal[0]) + __popcll(bal[1])
                       + __popcll(bal[2]) + __popcll(bal[3]));
        }
    }
}

// ---------------------------------------------------------------------------
extern "C" void kernel_launch(void* const* d_in, const int* in_sizes, int n_in,
                              void* d_out, int out_size, void* d_ws, size_t ws_size,
                              hipStream_t stream)
{
    const float2* pos2d  = (const float2*)d_in[0];
    const float*  radius = (const float*)d_in[1];
    const float*  depth  = (const float*)d_in[2];

    int* out32        = (int*)d_out;
    int* tile_count   = out32;             // [256] inclusive cumsum
    int* tile_indices = out32 + T_TILES;   // [256*65536]

    char* ws = (char*)d_ws;
    u64* keysRaw      = (u64*)(ws);                     // 512 KB (entries reuse)
    u64* keysBkt      = (u64*)(ws + 512 * 1024);        // 512 KB
    u32* bounds       = (u32*)(ws + 1024 * 1024);       // 256 KB
    u32* counts_blk   = (u32*)(ws + 1280 * 1024);       // 64 KB  (64 x 256)
    u32* bh           = (u32*)(ws + 1344 * 1024);       // 512 KB (64 x 2048)
    u32* bucket_base  = (u32*)(ws + 1856 * 1024);       // 8 KB
    u32* bucket_count = (u32*)(ws + 1864 * 1024);       // 8 KB

    k_compute<<<NBLK, 256, 0, stream>>>(pos2d, radius, depth, keysRaw, bounds,
                                        counts_blk, bh);
    k_scatter<<<NBLK, 256, 0, stream>>>(keysRaw, bh, keysBkt,
                                        bucket_base, bucket_count);

    u32* entries = (u32*)keysRaw;          // keysRaw dead after k_scatter
    k_bsort<<<NBKT / 4, 256, 0, stream>>>(keysBkt, bucket_base, bucket_count,
                                          bounds, entries);
    k_compact<<<CBLK, CTHR, 0, stream>>>((const uint4*)entries, counts_blk,
                                         tile_count, tile_indices);
}